// Round 6
// baseline (205.236 us; speedup 1.0000x reference)
//
#include <hip/hip_runtime.h>
#include <hip/hip_bf16.h>
#include <math.h>

typedef __bf16 bf16x8 __attribute__((ext_vector_type(8)));
typedef float f32x4 __attribute__((ext_vector_type(4)));

__device__ __forceinline__ unsigned short f2bf(float x) {
    union { float f; unsigned int u; } v; v.f = x;
    unsigned int r = v.u + 0x7fffu + ((v.u >> 16) & 1u);  // round-to-nearest-even
    return (unsigned short)(r >> 16);
}
__device__ __forceinline__ float bf2f(unsigned short h) {
    union { unsigned int u; float f; } v; v.u = ((unsigned int)h) << 16;
    return v.f;
}
__device__ __forceinline__ float gelu_exact(float v) {
    return 0.5f * v * (1.0f + erff(v * 0.70710678118654752f));
}

// ---------------------------------------------------------------------------
// prep: blocks [0,4096)   -> span pooling into hp (4096 x 3072 bf16)
//       blocks [4096,4864)-> W1 fp32 -> bf16 (256x3072); blk 4096 zeros cnt
//       blocks [4864,5888)-> zero xacc1 (4096x256 fp32)
// ---------------------------------------------------------------------------
__global__ __launch_bounds__(256) void prep_kernel(const float* __restrict__ hs,
                                                   const int* __restrict__ spans,
                                                   const float* __restrict__ W1,
                                                   unsigned short* __restrict__ hp,
                                                   unsigned short* __restrict__ w1b,
                                                   float* __restrict__ xacc1,
                                                   int* __restrict__ cnt) {
    const int blk = blockIdx.x;
    const int tid = threadIdx.x;

    if (blk >= 4096) {
        if (blk < 4864) {                     // W1 convert: 196608 float4s
            if (blk == 4096 && tid < 32) cnt[tid] = 0;
            const int i = (blk - 4096) * 256 + tid;
            float4 f = ((const float4*)W1)[i];
            ushort4 u;
            u.x = f2bf(f.x); u.y = f2bf(f.y); u.z = f2bf(f.z); u.w = f2bf(f.w);
            ((ushort4*)w1b)[i] = u;
        } else {                              // zero xacc1: 262144 float4s
            const int i = (blk - 4864) * 256 + tid;
            ((float4*)xacc1)[i] = make_float4(0.f, 0.f, 0.f, 0.f);
        }
        return;
    }

    const int pair = blk;                     // b*Q + q, Q=128
    const int b = pair >> 7;

    // dtype probe: int64 spans -> word 1 is high half of asp_s[0] (== 0);
    // int32 spans -> it's asp_e[0] which is always >= 2.
    const bool is64 = (spans[1] == 0);
    int s_a, e_a, s_o, e_o;
    if (is64) {
        s_a = spans[(pair * 4 + 0) * 2]; e_a = spans[(pair * 4 + 1) * 2];
        s_o = spans[(pair * 4 + 2) * 2]; e_o = spans[(pair * 4 + 3) * 2];
    } else {
        s_a = spans[pair * 4 + 0]; e_a = spans[pair * 4 + 1];
        s_o = spans[pair * 4 + 2]; e_o = spans[pair * 4 + 3];
    }

    const float4* base = (const float4*)hs + (size_t)b * 512 * 256;  // L=512, H/4=256

    float4 A, O;
    if (s_a >= 2 && e_a >= s_a) {
        float sx = 0.f, sy = 0.f, sz = 0.f, sw = 0.f;
        for (int t = s_a; t <= e_a; ++t) {
            float4 v = base[t * 256 + tid];
            sx += v.x; sy += v.y; sz += v.z; sw += v.w;
        }
        float inv = 1.0f / (float)(e_a - s_a + 1);
        A.x = sx * inv; A.y = sy * inv; A.z = sz * inv; A.w = sw * inv;
    } else {
        A = base[256 + tid];                  // sep token, row 1
    }
    if (s_o >= 2 && e_o >= s_o) {
        float sx = 0.f, sy = 0.f, sz = 0.f, sw = 0.f;
        for (int t = s_o; t <= e_o; ++t) {
            float4 v = base[t * 256 + tid];
            sx += v.x; sy += v.y; sz += v.z; sw += v.w;
        }
        float inv = 1.0f / (float)(e_o - s_o + 1);
        O.x = sx * inv; O.y = sy * inv; O.z = sz * inv; O.w = sw * inv;
    } else {
        O = base[256 + tid];
    }

    unsigned short* row = hp + (size_t)pair * 3072;
    const int d = tid * 4;
    ushort4 pa, po, pp;
    pa.x = f2bf(A.x); pa.y = f2bf(A.y); pa.z = f2bf(A.z); pa.w = f2bf(A.w);
    po.x = f2bf(O.x); po.y = f2bf(O.y); po.z = f2bf(O.z); po.w = f2bf(O.w);
    pp.x = f2bf(A.x * O.x); pp.y = f2bf(A.y * O.y);
    pp.z = f2bf(A.z * O.z); pp.w = f2bf(A.w * O.w);
    *(ushort4*)(row + d) = pa;
    *(ushort4*)(row + 1024 + d) = po;
    *(ushort4*)(row + 2048 + d) = pp;
}

// ---------------------------------------------------------------------------
// Fused GEMM1 (split-K atomics) + last-arriver finalize:
//   main: xacc += hp(128xK-chunk) @ w1b^T, grid (32,2,8), BM=BN=128, BK=64.
//   last of the 16 blocks per m-tile: x1 = gelu(xacc+b1) (coherent re-read),
//   x2 = gelu(x1 @ W2^T + b2) via MFMA (W2 converted in-stage),
//   out = sigmoid(x2 . W3^T + b3)*8+1, masked. All on-chip (LDS).
// XOR chunk swizzle on LDS layout (both stage + read sides) -> bank-uniform.
// ---------------------------------------------------------------------------
__global__ __launch_bounds__(256, 2) void gemm_fused(const unsigned short* __restrict__ A,
                                                     const unsigned short* __restrict__ Bw,
                                                     float* __restrict__ xacc,
                                                     const float* __restrict__ b1,
                                                     const float* __restrict__ W2f,
                                                     const float* __restrict__ b2,
                                                     const float* __restrict__ W3,
                                                     const float* __restrict__ b3,
                                                     const float* __restrict__ mask,
                                                     float* __restrict__ out,
                                                     int* __restrict__ cnt) {
    // smem partition: main/GEMM2 staging uses As=smem[0:8192], Bs=smem[8192:16384]
    // (halfwords); finalize x2 tile uses smem as [128][136] bf16 (17408 hw).
    __shared__ __align__(16) unsigned short smem[17408];
    __shared__ int s_last;
    unsigned short* As = smem;
    unsigned short* Bs = smem + 8192;

    const int tid = threadIdx.x;
    const int lane = tid & 63;
    const int wid = tid >> 6;
    const int quad = lane >> 4;
    const int l16 = lane & 15;
    const int wM = (wid >> 1) * 64;
    const int wN = (wid & 1) * 64;
    const int m0 = blockIdx.x * 128;
    const int n0 = blockIdx.y * 128;
    const int kb = blockIdx.z * 384;

    // staging source: slot (j*256+tid) -> row = j*32 + (tid>>3), pchunk = tid&7
    const int srow = tid >> 3;
    const int lchunk = (tid & 7) ^ (srow & 7);
    const unsigned short* Abase = A + (size_t)(m0 + srow) * 3072 + kb + lchunk * 8;
    const unsigned short* Bbase = Bw + (size_t)(n0 + srow) * 3072 + kb + lchunk * 8;

    // fragment LDS offsets (halfwords), fixed; same geometry for GEMM1+GEMM2
    int aoff[4][2], boff[4][2];
#pragma unroll
    for (int mi = 0; mi < 4; ++mi) {
#pragma unroll
        for (int h = 0; h < 2; ++h) {
            int row = wM + mi * 16 + l16;
            int pc = (h * 4 + quad) ^ (row & 7);
            aoff[mi][h] = row * 64 + pc * 8;
            row = wN + mi * 16 + l16;
            pc = (h * 4 + quad) ^ (row & 7);
            boff[mi][h] = row * 64 + pc * 8;
        }
    }

    {
        f32x4 acc[4][4] = {};
#pragma unroll
        for (int it = 0; it < 6; ++it) {
            const int kadv = it * 64;         // halfwords along K
#pragma unroll
            for (int j = 0; j < 4; ++j) {
                __builtin_amdgcn_global_load_lds(
                    (const __attribute__((address_space(1))) void*)(Abase + (size_t)j * 32 * 3072 + kadv),
                    (__attribute__((address_space(3))) void*)(&As[(j * 256 + tid) * 8]),
                    16, 0, 0);
                __builtin_amdgcn_global_load_lds(
                    (const __attribute__((address_space(1))) void*)(Bbase + (size_t)j * 32 * 3072 + kadv),
                    (__attribute__((address_space(3))) void*)(&Bs[(j * 256 + tid) * 8]),
                    16, 0, 0);
            }
            __syncthreads();
#pragma unroll
            for (int h = 0; h < 2; ++h) {
                bf16x8 af[4], bfr[4];
#pragma unroll
                for (int mi = 0; mi < 4; ++mi) af[mi] = *(const bf16x8*)&As[aoff[mi][h]];
#pragma unroll
                for (int ni = 0; ni < 4; ++ni) bfr[ni] = *(const bf16x8*)&Bs[boff[ni][h]];
#pragma unroll
                for (int mi = 0; mi < 4; ++mi)
#pragma unroll
                    for (int ni = 0; ni < 4; ++ni)
                        acc[mi][ni] = __builtin_amdgcn_mfma_f32_16x16x32_bf16(
                            af[mi], bfr[ni], acc[mi][ni], 0, 0, 0);
            }
            __syncthreads();
        }

#pragma unroll
        for (int mi = 0; mi < 4; ++mi) {
#pragma unroll
            for (int ni = 0; ni < 4; ++ni) {
                const int n = n0 + wN + ni * 16 + l16;
#pragma unroll
                for (int rr = 0; rr < 4; ++rr) {
                    const int m = m0 + wM + mi * 16 + quad * 4 + rr;
                    unsafeAtomicAdd(&xacc[(size_t)m * 256 + n], acc[mi][ni][rr]);
                }
            }
        }
    }

    // ---- last-arriver election (16 blocks per m-tile: y in {0,1} x z in {0..7})
    __syncthreads();                          // drains this block's atomics (vmcnt 0)
    if (tid == 0) {
        __threadfence();
        int old = __hip_atomic_fetch_add(&cnt[blockIdx.x], 1,
                                         __ATOMIC_ACQ_REL, __HIP_MEMORY_SCOPE_AGENT);
        s_last = (old == 15) ? 1 : 0;
    }
    __syncthreads();
    if (!s_last) return;

    // ---- finalize this m-tile: GEMM2 (128x128x256) + head, all on-chip
    f32x4 acc2[4][4] = {};
#pragma unroll
    for (int kc = 0; kc < 4; ++kc) {
#pragma unroll
        for (int s4 = 0; s4 < 4; ++s4) {
            const int s = s4 * 256 + tid;     // 0..1023
            const int row = s >> 3;           // 0..127
            const int pc = s & 7;
            const int lc = pc ^ (row & 7);
            const int col = kc * 64 + lc * 8;
            // x1 chunk: coherent read of xacc (other XCDs' atomics!), +b1, gelu
            const float* xsrc = xacc + (size_t)(m0 + row) * 256 + col;
            float v[8];
#pragma unroll
            for (int j = 0; j < 8; ++j)
                v[j] = __hip_atomic_load(xsrc + j, __ATOMIC_RELAXED,
                                         __HIP_MEMORY_SCOPE_AGENT);
            ushort4 u0, u1;
            u0.x = f2bf(gelu_exact(v[0] + b1[col + 0]));
            u0.y = f2bf(gelu_exact(v[1] + b1[col + 1]));
            u0.z = f2bf(gelu_exact(v[2] + b1[col + 2]));
            u0.w = f2bf(gelu_exact(v[3] + b1[col + 3]));
            u1.x = f2bf(gelu_exact(v[4] + b1[col + 4]));
            u1.y = f2bf(gelu_exact(v[5] + b1[col + 5]));
            u1.z = f2bf(gelu_exact(v[6] + b1[col + 6]));
            u1.w = f2bf(gelu_exact(v[7] + b1[col + 7]));
            *(ushort4*)&As[s * 8] = u0;
            *(ushort4*)&As[s * 8 + 4] = u1;
            // W2 chunk fp32 -> bf16
            const float* wsrc = W2f + (size_t)row * 256 + col;
            float4 f0 = *(const float4*)wsrc;
            float4 f1 = *(const float4*)(wsrc + 4);
            u0.x = f2bf(f0.x); u0.y = f2bf(f0.y); u0.z = f2bf(f0.z); u0.w = f2bf(f0.w);
            u1.x = f2bf(f1.x); u1.y = f2bf(f1.y); u1.z = f2bf(f1.z); u1.w = f2bf(f1.w);
            *(ushort4*)&Bs[s * 8] = u0;
            *(ushort4*)&Bs[s * 8 + 4] = u1;
        }
        __syncthreads();
#pragma unroll
        for (int h = 0; h < 2; ++h) {
            bf16x8 af[4], bfr[4];
#pragma unroll
            for (int mi = 0; mi < 4; ++mi) af[mi] = *(const bf16x8*)&As[aoff[mi][h]];
#pragma unroll
            for (int ni = 0; ni < 4; ++ni) bfr[ni] = *(const bf16x8*)&Bs[boff[ni][h]];
#pragma unroll
            for (int mi = 0; mi < 4; ++mi)
#pragma unroll
                for (int ni = 0; ni < 4; ++ni)
                    acc2[mi][ni] = __builtin_amdgcn_mfma_f32_16x16x32_bf16(
                        af[mi], bfr[ni], acc2[mi][ni], 0, 0, 0);
        }
        __syncthreads();
    }

    // x2 = gelu(acc2 + b2) -> smem as [128][136] bf16
#pragma unroll
    for (int mi = 0; mi < 4; ++mi) {
#pragma unroll
        for (int ni = 0; ni < 4; ++ni) {
            const int col = wN + ni * 16 + l16;
            const float bn = b2[col];
#pragma unroll
            for (int rr = 0; rr < 4; ++rr) {
                const int row = wM + mi * 16 + quad * 4 + rr;
                smem[row * 136 + col] = f2bf(gelu_exact(acc2[mi][ni][rr] + bn));
            }
        }
    }
    __syncthreads();

    // head: 2 threads per pair, 64 cols each
    const int p = tid >> 1;                   // 0..127
    const int half = (tid & 1) * 64;
    float a0 = 0.f, a1 = 0.f;
#pragma unroll
    for (int j = 0; j < 64; ++j) {
        const float xv = bf2f(smem[p * 136 + half + j]);
        a0 += xv * W3[half + j];
        a1 += xv * W3[128 + half + j];
    }
    a0 += __shfl_xor(a0, 1);
    a1 += __shfl_xor(a1, 1);
    if ((tid & 1) == 0) {
        const int pair = m0 + p;
        const float mk = (mask[pair] >= 0.5f) ? 1.0f : 0.0f;
        out[pair * 2 + 0] = ((1.0f / (1.0f + expf(-(a0 + b3[0])))) * 8.0f + 1.0f) * mk;
        out[pair * 2 + 1] = ((1.0f / (1.0f + expf(-(a1 + b3[1])))) * 8.0f + 1.0f) * mk;
    }
}

// ---------------------------------------------------------------------------
extern "C" void kernel_launch(void* const* d_in, const int* in_sizes, int n_in,
                              void* d_out, int out_size, void* d_ws, size_t ws_size,
                              hipStream_t stream) {
    const float* hs   = (const float*)d_in[0];
    const int*   spans= (const int*)d_in[1];
    const float* mask = (const float*)d_in[2];
    const float* W1   = (const float*)d_in[3];
    const float* b1   = (const float*)d_in[4];
    const float* W2   = (const float*)d_in[5];
    const float* b2   = (const float*)d_in[6];
    const float* W3   = (const float*)d_in[7];
    const float* b3   = (const float*)d_in[8];
    float* out = (float*)d_out;

    // ws: hp bf16 4096x3072 [0, 25165824); xacc1 fp32 4096x256 [25165824, +4MB);
    // w1b bf16 256x3072 [29360128, +1.5MB); cnt int32 x32 [30932992, +128B).
    unsigned short* hp    = (unsigned short*)d_ws;
    float*          xacc1 = (float*)((char*)d_ws + 25165824);
    unsigned short* w1b   = (unsigned short*)((char*)d_ws + 29360128);
    int*            cnt   = (int*)((char*)d_ws + 30932992);

    prep_kernel<<<dim3(5888), dim3(256), 0, stream>>>(hs, spans, W1, hp, w1b, xacc1, cnt);
    gemm_fused<<<dim3(32, 2, 8), dim3(256), 0, stream>>>(hp, w1b, xacc1, b1, W2, b2,
                                                         W3, b3, mask, out, cnt);
}

// Round 7
// 161.271 us; speedup vs baseline: 1.2726x; 1.2726x over previous
//
#include <hip/hip_runtime.h>
#include <hip/hip_bf16.h>
#include <math.h>

typedef __bf16 bf16x8 __attribute__((ext_vector_type(8)));
typedef float f32x4 __attribute__((ext_vector_type(4)));

__device__ __forceinline__ unsigned short f2bf(float x) {
    union { float f; unsigned int u; } v; v.f = x;
    unsigned int r = v.u + 0x7fffu + ((v.u >> 16) & 1u);  // round-to-nearest-even
    return (unsigned short)(r >> 16);
}
__device__ __forceinline__ float gelu_exact(float v) {
    return 0.5f * v * (1.0f + erff(v * 0.70710678118654752f));
}

// ---------------------------------------------------------------------------
// prep: blocks [0,4096)   -> span pooling into hp (4096 x 3072 bf16)
//       blocks [4096,4864)-> W1 fp32 -> bf16 (256x3072)
//       blocks [4864,5888)-> zero xacc1 (4096x256 fp32)
// ---------------------------------------------------------------------------
__global__ __launch_bounds__(256) void prep_kernel(const float* __restrict__ hs,
                                                   const int* __restrict__ spans,
                                                   const float* __restrict__ W1,
                                                   unsigned short* __restrict__ hp,
                                                   unsigned short* __restrict__ w1b,
                                                   float* __restrict__ xacc1) {
    const int blk = blockIdx.x;
    const int tid = threadIdx.x;

    if (blk >= 4096) {
        if (blk < 4864) {                     // W1 convert: 196608 float4s
            const int i = (blk - 4096) * 256 + tid;
            float4 f = ((const float4*)W1)[i];
            ushort4 u;
            u.x = f2bf(f.x); u.y = f2bf(f.y); u.z = f2bf(f.z); u.w = f2bf(f.w);
            ((ushort4*)w1b)[i] = u;
        } else {                              // zero xacc1: 262144 float4s
            const int i = (blk - 4864) * 256 + tid;
            ((float4*)xacc1)[i] = make_float4(0.f, 0.f, 0.f, 0.f);
        }
        return;
    }

    const int pair = blk;                     // b*Q + q, Q=128
    const int b = pair >> 7;

    // dtype probe: int64 spans -> word 1 is high half of asp_s[0] (== 0);
    // int32 spans -> it's asp_e[0] which is always >= 2.
    const bool is64 = (spans[1] == 0);
    int s_a, e_a, s_o, e_o;
    if (is64) {
        s_a = spans[(pair * 4 + 0) * 2]; e_a = spans[(pair * 4 + 1) * 2];
        s_o = spans[(pair * 4 + 2) * 2]; e_o = spans[(pair * 4 + 3) * 2];
    } else {
        s_a = spans[pair * 4 + 0]; e_a = spans[pair * 4 + 1];
        s_o = spans[pair * 4 + 2]; e_o = spans[pair * 4 + 3];
    }

    const float4* base = (const float4*)hs + (size_t)b * 512 * 256;  // L=512, H/4=256

    float4 A, O;
    if (s_a >= 2 && e_a >= s_a) {
        float sx = 0.f, sy = 0.f, sz = 0.f, sw = 0.f;
        for (int t = s_a; t <= e_a; ++t) {
            float4 v = base[t * 256 + tid];
            sx += v.x; sy += v.y; sz += v.z; sw += v.w;
        }
        float inv = 1.0f / (float)(e_a - s_a + 1);
        A.x = sx * inv; A.y = sy * inv; A.z = sz * inv; A.w = sw * inv;
    } else {
        A = base[256 + tid];                  // sep token, row 1
    }
    if (s_o >= 2 && e_o >= s_o) {
        float sx = 0.f, sy = 0.f, sz = 0.f, sw = 0.f;
        for (int t = s_o; t <= e_o; ++t) {
            float4 v = base[t * 256 + tid];
            sx += v.x; sy += v.y; sz += v.z; sw += v.w;
        }
        float inv = 1.0f / (float)(e_o - s_o + 1);
        O.x = sx * inv; O.y = sy * inv; O.z = sz * inv; O.w = sw * inv;
    } else {
        O = base[256 + tid];
    }

    unsigned short* row = hp + (size_t)pair * 3072;
    const int d = tid * 4;
    ushort4 pa, po, pp;
    pa.x = f2bf(A.x); pa.y = f2bf(A.y); pa.z = f2bf(A.z); pa.w = f2bf(A.w);
    po.x = f2bf(O.x); po.y = f2bf(O.y); po.z = f2bf(O.z); po.w = f2bf(O.w);
    pp.x = f2bf(A.x * O.x); pp.y = f2bf(A.y * O.y);
    pp.z = f2bf(A.z * O.z); pp.w = f2bf(A.w * O.w);
    *(ushort4*)(row + d) = pa;
    *(ushort4*)(row + 1024 + d) = po;
    *(ushort4*)(row + 2048 + d) = pp;
}

// ---------------------------------------------------------------------------
// GEMM1 split-K atomics, high-occupancy shape:
// xacc += A @ Bw^T. A: 4096x3072 bf16 (hp). Bw: 256x3072 bf16 (w1b).
// BM=128, BN=64, BK=64, S=8 (Ks=384, 6 iters). grid (32,4,8) = 1024 blocks.
// LDS = 16KB (As) + 8KB (Bs) = 24KB -> ~6 blocks/CU, ~24 waves/CU.
// 4 waves stacked along M: wave tile 32x64 = 2x4 x mfma_16x16x32_bf16.
// global_load_lds width=16 staging; XOR chunk swizzle on LDS layout
// (stage + read sides agree) -> bank-uniform ds_read_b128.
// ---------------------------------------------------------------------------
__global__ __launch_bounds__(256, 4) void gemm1_mfma(const unsigned short* __restrict__ A,
                                                     const unsigned short* __restrict__ Bw,
                                                     float* __restrict__ xacc) {
    __shared__ __align__(16) unsigned short As[128 * 64];
    __shared__ __align__(16) unsigned short Bs[64 * 64];

    const int tid = threadIdx.x;
    const int lane = tid & 63;
    const int wid = tid >> 6;
    const int quad = lane >> 4;
    const int l16 = lane & 15;
    const int wM = wid * 32;
    const int m0 = blockIdx.x * 128;
    const int n0 = blockIdx.y * 64;
    const int kb = blockIdx.z * 384;

    // staging source: slot (j*256+tid) -> row = j*32 + (tid>>3), pchunk = tid&7
    const int srow = tid >> 3;
    const int lchunk = (tid & 7) ^ (srow & 7);
    const unsigned short* Abase = A + (size_t)(m0 + srow) * 3072 + kb + lchunk * 8;
    const unsigned short* Bbase = Bw + (size_t)(n0 + srow) * 3072 + kb + lchunk * 8;

    // fragment LDS offsets (halfwords), fixed across iters
    int aoff[2][2], boff[4][2];
#pragma unroll
    for (int h = 0; h < 2; ++h) {
#pragma unroll
        for (int mi = 0; mi < 2; ++mi) {
            const int row = wM + mi * 16 + l16;
            const int pc = (h * 4 + quad) ^ (row & 7);
            aoff[mi][h] = row * 64 + pc * 8;
        }
#pragma unroll
        for (int ni = 0; ni < 4; ++ni) {
            const int row = ni * 16 + l16;
            const int pc = (h * 4 + quad) ^ (row & 7);
            boff[ni][h] = row * 64 + pc * 8;
        }
    }

    f32x4 acc[2][4] = {};

#pragma unroll
    for (int it = 0; it < 6; ++it) {
        const int kadv = it * 64;             // halfwords along K
#pragma unroll
        for (int j = 0; j < 4; ++j) {         // A: 1024 slots
            __builtin_amdgcn_global_load_lds(
                (const __attribute__((address_space(1))) void*)(Abase + (size_t)j * 32 * 3072 + kadv),
                (__attribute__((address_space(3))) void*)(&As[(j * 256 + tid) * 8]),
                16, 0, 0);
        }
#pragma unroll
        for (int j = 0; j < 2; ++j) {         // B: 512 slots
            __builtin_amdgcn_global_load_lds(
                (const __attribute__((address_space(1))) void*)(Bbase + (size_t)j * 32 * 3072 + kadv),
                (__attribute__((address_space(3))) void*)(&Bs[(j * 256 + tid) * 8]),
                16, 0, 0);
        }
        __syncthreads();
#pragma unroll
        for (int h = 0; h < 2; ++h) {
            bf16x8 af[2], bfr[4];
#pragma unroll
            for (int mi = 0; mi < 2; ++mi) af[mi] = *(const bf16x8*)&As[aoff[mi][h]];
#pragma unroll
            for (int ni = 0; ni < 4; ++ni) bfr[ni] = *(const bf16x8*)&Bs[boff[ni][h]];
#pragma unroll
            for (int mi = 0; mi < 2; ++mi)
#pragma unroll
                for (int ni = 0; ni < 4; ++ni)
                    acc[mi][ni] = __builtin_amdgcn_mfma_f32_16x16x32_bf16(
                        af[mi], bfr[ni], acc[mi][ni], 0, 0, 0);
        }
        __syncthreads();
    }

#pragma unroll
    for (int mi = 0; mi < 2; ++mi) {
#pragma unroll
        for (int ni = 0; ni < 4; ++ni) {
            const int n = n0 + ni * 16 + l16;
#pragma unroll
            for (int rr = 0; rr < 4; ++rr) {
                const int m = m0 + wM + mi * 16 + quad * 4 + rr;
                unsafeAtomicAdd(&xacc[(size_t)m * 256 + n], acc[mi][ni][rr]);
            }
        }
    }
}

// ---------------------------------------------------------------------------
// Fused bias1+GELU + GEMM2 + bias2+GELU + head: 32 pairs/block, grid 128.
// Stages Xs directly from the fp32 accumulator (bias+gelu at LDS-write time).
// ---------------------------------------------------------------------------
__global__ __launch_bounds__(256) void mlp2g_head(const float* __restrict__ xacc,
                                                  const float* __restrict__ b1,
                                                  const float* __restrict__ W2f,
                                                  const float* __restrict__ b2,
                                                  const float* __restrict__ W3,
                                                  const float* __restrict__ b3,
                                                  const float* __restrict__ mask,
                                                  float* __restrict__ out) {
    __shared__ __align__(16) unsigned short Xs[32][72];
    __shared__ __align__(16) unsigned short Ws[128][72];
    __shared__ float X2[32][132];

    const int tid = threadIdx.x;
    const int lane = tid & 63;
    const int wid = tid >> 6;
    const int wM = (wid >> 1) * 16;   // waves 2x2: wave tile 16 x 64
    const int wN = (wid & 1) * 64;
    const int quad = lane >> 4;
    const int l16 = lane & 15;
    const int m0 = blockIdx.x * 32;

    f32x4 acc[4] = {};

    for (int k0 = 0; k0 < 256; k0 += 64) {
        {   // stage Xs 32x64: read xacc fp32, +b1, gelu, pack bf16
            const int r = tid >> 3, c = (tid & 7) * 8;
            const float* src = xacc + (size_t)(m0 + r) * 256 + k0 + c;
            float4 f0 = *(const float4*)src;
            float4 f1 = *(const float4*)(src + 4);
            float4 g0 = *(const float4*)(b1 + k0 + c);
            float4 g1 = *(const float4*)(b1 + k0 + c + 4);
            ushort4 u0, u1;
            u0.x = f2bf(gelu_exact(f0.x + g0.x)); u0.y = f2bf(gelu_exact(f0.y + g0.y));
            u0.z = f2bf(gelu_exact(f0.z + g0.z)); u0.w = f2bf(gelu_exact(f0.w + g0.w));
            u1.x = f2bf(gelu_exact(f1.x + g1.x)); u1.y = f2bf(gelu_exact(f1.y + g1.y));
            u1.z = f2bf(gelu_exact(f1.z + g1.z)); u1.w = f2bf(gelu_exact(f1.w + g1.w));
            *(ushort4*)&Xs[r][c] = u0;
            *(ushort4*)&Xs[r][c + 4] = u1;
        }
#pragma unroll
        for (int p = 0; p < 4; ++p) {   // stage Ws 128x64 from fp32
            const int v = tid + p * 256;
            const int r = v >> 3, c = (v & 7) * 8;
            const float* src = W2f + (size_t)r * 256 + k0 + c;
            float4 f0 = *(const float4*)src;
            float4 f1 = *(const float4*)(src + 4);
            ushort4 u;
            u.x = f2bf(f0.x); u.y = f2bf(f0.y); u.z = f2bf(f0.z); u.w = f2bf(f0.w);
            *(ushort4*)&Ws[r][c] = u;
            u.x = f2bf(f1.x); u.y = f2bf(f1.y); u.z = f2bf(f1.z); u.w = f2bf(f1.w);
            *(ushort4*)&Ws[r][c + 4] = u;
        }
        __syncthreads();
#pragma unroll
        for (int kk = 0; kk < 64; kk += 32) {
            bf16x8 a = *(const bf16x8*)&Xs[wM + l16][kk + quad * 8];
#pragma unroll
            for (int ni = 0; ni < 4; ++ni) {
                bf16x8 b = *(const bf16x8*)&Ws[wN + ni * 16 + l16][kk + quad * 8];
                acc[ni] = __builtin_amdgcn_mfma_f32_16x16x32_bf16(a, b, acc[ni], 0, 0, 0);
            }
        }
        __syncthreads();
    }

#pragma unroll
    for (int ni = 0; ni < 4; ++ni) {
        const int n = wN + ni * 16 + l16;
        const float bn = b2[n];
#pragma unroll
        for (int rr = 0; rr < 4; ++rr) {
            const int m = wM + quad * 4 + rr;
            X2[m][n] = gelu_exact(acc[ni][rr] + bn);
        }
    }
    __syncthreads();

    const int p = tid >> 3;           // pair-in-block 0..31
    const int cc = (tid & 7) * 16;
    float a0 = 0.f, a1 = 0.f;
#pragma unroll
    for (int j = 0; j < 16; ++j) {
        const float xv = X2[p][cc + j];
        a0 += xv * W3[cc + j];
        a1 += xv * W3[128 + cc + j];
    }
    a0 += __shfl_xor(a0, 1); a0 += __shfl_xor(a0, 2); a0 += __shfl_xor(a0, 4);
    a1 += __shfl_xor(a1, 1); a1 += __shfl_xor(a1, 2); a1 += __shfl_xor(a1, 4);
    if ((tid & 7) == 0) {
        const int pair = m0 + p;
        const float mk = (mask[pair] >= 0.5f) ? 1.0f : 0.0f;
        out[pair * 2 + 0] = ((1.0f / (1.0f + expf(-(a0 + b3[0])))) * 8.0f + 1.0f) * mk;
        out[pair * 2 + 1] = ((1.0f / (1.0f + expf(-(a1 + b3[1])))) * 8.0f + 1.0f) * mk;
    }
}

// ---------------------------------------------------------------------------
extern "C" void kernel_launch(void* const* d_in, const int* in_sizes, int n_in,
                              void* d_out, int out_size, void* d_ws, size_t ws_size,
                              hipStream_t stream) {
    const float* hs   = (const float*)d_in[0];
    const int*   spans= (const int*)d_in[1];
    const float* mask = (const float*)d_in[2];
    const float* W1   = (const float*)d_in[3];
    const float* b1   = (const float*)d_in[4];
    const float* W2   = (const float*)d_in[5];
    const float* b2   = (const float*)d_in[6];
    const float* W3   = (const float*)d_in[7];
    const float* b3   = (const float*)d_in[8];
    float* out = (float*)d_out;

    // ws: hp bf16 4096x3072 [0, 25165824); xacc1 fp32 4096x256 [25165824, +4MB);
    // w1b bf16 256x3072 [29360128, +1.5MB).
    unsigned short* hp    = (unsigned short*)d_ws;
    float*          xacc1 = (float*)((char*)d_ws + 25165824);
    unsigned short* w1b   = (unsigned short*)((char*)d_ws + 29360128);

    prep_kernel<<<dim3(5888), dim3(256), 0, stream>>>(hs, spans, W1, hp, w1b, xacc1);
    gemm1_mfma<<<dim3(32, 4, 8), dim3(256), 0, stream>>>(hp, w1b, xacc1);
    mlp2g_head<<<dim3(128), dim3(256), 0, stream>>>(xacc1, b1, W2, b2, W3, b3, mask, out);
}

// Round 8
// 158.626 us; speedup vs baseline: 1.2938x; 1.0167x over previous
//
#include <hip/hip_runtime.h>
#include <hip/hip_bf16.h>
#include <math.h>

typedef __bf16 bf16x8 __attribute__((ext_vector_type(8)));
typedef float f32x4 __attribute__((ext_vector_type(4)));

__device__ __forceinline__ unsigned short f2bf(float x) {
    union { float f; unsigned int u; } v; v.f = x;
    unsigned int r = v.u + 0x7fffu + ((v.u >> 16) & 1u);  // round-to-nearest-even
    return (unsigned short)(r >> 16);
}
__device__ __forceinline__ float bf2f(unsigned short h) {
    union { unsigned int u; float f; } v; v.u = ((unsigned int)h) << 16;
    return v.f;
}
__device__ __forceinline__ float gelu_exact(float v) {
    return 0.5f * v * (1.0f + erff(v * 0.70710678118654752f));
}

// ---------------------------------------------------------------------------
// prep: blocks [0,4096)   -> span pooling into hp (4096 x 3072 bf16)
//       blocks [4096,4864)-> W1 fp32 -> bf16 (256x3072)
// ---------------------------------------------------------------------------
__global__ __launch_bounds__(256) void prep_kernel(const float* __restrict__ hs,
                                                   const int* __restrict__ spans,
                                                   const float* __restrict__ W1,
                                                   unsigned short* __restrict__ hp,
                                                   unsigned short* __restrict__ w1b) {
    const int blk = blockIdx.x;
    const int tid = threadIdx.x;

    if (blk >= 4096) {                        // W1 convert: 196608 float4s
        const int i = (blk - 4096) * 256 + tid;
        float4 f = ((const float4*)W1)[i];
        ushort4 u;
        u.x = f2bf(f.x); u.y = f2bf(f.y); u.z = f2bf(f.z); u.w = f2bf(f.w);
        ((ushort4*)w1b)[i] = u;
        return;
    }

    const int pair = blk;                     // b*Q + q, Q=128
    const int b = pair >> 7;

    // dtype probe: int64 spans -> word 1 is high half of asp_s[0] (== 0);
    // int32 spans -> it's asp_e[0] which is always >= 2.
    const bool is64 = (spans[1] == 0);
    int s_a, e_a, s_o, e_o;
    if (is64) {
        s_a = spans[(pair * 4 + 0) * 2]; e_a = spans[(pair * 4 + 1) * 2];
        s_o = spans[(pair * 4 + 2) * 2]; e_o = spans[(pair * 4 + 3) * 2];
    } else {
        s_a = spans[pair * 4 + 0]; e_a = spans[pair * 4 + 1];
        s_o = spans[pair * 4 + 2]; e_o = spans[pair * 4 + 3];
    }

    const float4* base = (const float4*)hs + (size_t)b * 512 * 256;  // L=512, H/4=256

    float4 A, O;
    if (s_a >= 2 && e_a >= s_a) {
        float sx = 0.f, sy = 0.f, sz = 0.f, sw = 0.f;
        for (int t = s_a; t <= e_a; ++t) {
            float4 v = base[t * 256 + tid];
            sx += v.x; sy += v.y; sz += v.z; sw += v.w;
        }
        float inv = 1.0f / (float)(e_a - s_a + 1);
        A.x = sx * inv; A.y = sy * inv; A.z = sz * inv; A.w = sw * inv;
    } else {
        A = base[256 + tid];                  // sep token, row 1
    }
    if (s_o >= 2 && e_o >= s_o) {
        float sx = 0.f, sy = 0.f, sz = 0.f, sw = 0.f;
        for (int t = s_o; t <= e_o; ++t) {
            float4 v = base[t * 256 + tid];
            sx += v.x; sy += v.y; sz += v.z; sw += v.w;
        }
        float inv = 1.0f / (float)(e_o - s_o + 1);
        O.x = sx * inv; O.y = sy * inv; O.z = sz * inv; O.w = sw * inv;
    } else {
        O = base[256 + tid];
    }

    unsigned short* row = hp + (size_t)pair * 3072;
    const int d = tid * 4;
    ushort4 pa, po, pp;
    pa.x = f2bf(A.x); pa.y = f2bf(A.y); pa.z = f2bf(A.z); pa.w = f2bf(A.w);
    po.x = f2bf(O.x); po.y = f2bf(O.y); po.z = f2bf(O.z); po.w = f2bf(O.w);
    pp.x = f2bf(A.x * O.x); pp.y = f2bf(A.y * O.y);
    pp.z = f2bf(A.z * O.z); pp.w = f2bf(A.w * O.w);
    *(ushort4*)(row + d) = pa;
    *(ushort4*)(row + 1024 + d) = po;
    *(ushort4*)(row + 2048 + d) = pp;
}

// ---------------------------------------------------------------------------
// mlp_all: the entire MLP + head in one kernel, no split-K, no atomics.
// Block = 16 pairs (BM=16), grid 256 (1 block/CU). 256 threads = 4 waves.
// Phase 1: x1acc = hp[16xK] @ w1b^T (K=3072, 48 iters, N=256; wave owns 64 N).
//   Double-buffered global_load_lds staging, ONE barrier per iter:
//   sync -> issue next-tile loads (async) -> compute current. The vmcnt(0)
//   at the next barrier drains them exactly when needed.
// Phase 2 (LDS reuse): x1 = gelu(acc+b1) -> bf16 LDS; W2 fp32->bf16 LDS;
//   GEMM2 16x128xK256; x2 = gelu(+b2) -> fp32 LDS; head dot + sigmoid + mask.
// XOR chunk swizzle on phase-1 LDS (stage+read agree) -> <=2-way banks (free).
// ---------------------------------------------------------------------------
__global__ __launch_bounds__(256) void mlp_all(const unsigned short* __restrict__ hp,
                                               const unsigned short* __restrict__ w1b,
                                               const float* __restrict__ b1,
                                               const float* __restrict__ W2f,
                                               const float* __restrict__ b2,
                                               const float* __restrict__ W3,
                                               const float* __restrict__ b3,
                                               const float* __restrict__ mask,
                                               float* __restrict__ out) {
    __shared__ __align__(16) unsigned char smem[84480];
    // phase 1 layout
    unsigned short* Ab0 = (unsigned short*)smem;              // 1024 hw
    unsigned short* Ab1 = (unsigned short*)(smem + 2048);     // 1024 hw
    unsigned short* Bb0 = (unsigned short*)(smem + 4096);     // 16384 hw
    unsigned short* Bb1 = (unsigned short*)(smem + 36864);    // 16384 hw
    // phase 2 layout (reuses phase-1 space)
    unsigned short* x1s = (unsigned short*)smem;              // 16 x 264 hw
    unsigned short* w2s = (unsigned short*)(smem + 8448);     // 128 x 264 hw
    float*          x2s = (float*)(smem + 76032);             // 16 x 132 f32

    const int tid = threadIdx.x;
    const int lane = tid & 63;
    const int wid = tid >> 6;
    const int quad = lane >> 4;
    const int l16 = lane & 15;
    const int m0 = blockIdx.x * 16;

    // phase-1 staging source pointers (XOR chunk swizzle; row&7 pattern is
    // identical for A rows (tid>>3 in [0,16)) and all B row groups (+j*32))
    const int srow = tid >> 3;
    const int lch = (tid & 7) ^ (srow & 7);
    const unsigned short* Aptr = hp + (size_t)(m0 + srow) * 3072 + lch * 8;
    const unsigned short* Bptr = w1b + (size_t)srow * 3072 + lch * 8;

    // phase-1 fragment LDS offsets (halfwords)
    int aoff[2], boff[4][2];
#pragma unroll
    for (int h = 0; h < 2; ++h) {
        {
            const int pc = (h * 4 + quad) ^ (l16 & 7);
            aoff[h] = l16 * 64 + pc * 8;
        }
#pragma unroll
        for (int ni = 0; ni < 4; ++ni) {
            const int row = wid * 64 + ni * 16 + l16;
            const int pc = (h * 4 + quad) ^ (row & 7);
            boff[ni][h] = row * 64 + pc * 8;
        }
    }

    f32x4 acc[4] = {};

    // prologue: stage tile 0 into buffer 0
    if (tid < 128)
        __builtin_amdgcn_global_load_lds(
            (const __attribute__((address_space(1))) void*)Aptr,
            (__attribute__((address_space(3))) void*)(Ab0 + tid * 8), 16, 0, 0);
#pragma unroll
    for (int j = 0; j < 8; ++j)
        __builtin_amdgcn_global_load_lds(
            (const __attribute__((address_space(1))) void*)(Bptr + (size_t)j * 32 * 3072),
            (__attribute__((address_space(3))) void*)(Bb0 + (j * 256 + tid) * 8), 16, 0, 0);

    for (int it = 0; it < 48; ++it) {
        unsigned short* Ac = (it & 1) ? Ab1 : Ab0;
        unsigned short* Bc = (it & 1) ? Bb1 : Bb0;
        __syncthreads();                      // drains pending stage (vmcnt 0)
        if (it + 1 < 48) {                    // issue next tile into other buffer
            unsigned short* An = (it & 1) ? Ab0 : Ab1;
            unsigned short* Bn = (it & 1) ? Bb0 : Bb1;
            const int kadv = (it + 1) * 64;
            if (tid < 128)
                __builtin_amdgcn_global_load_lds(
                    (const __attribute__((address_space(1))) void*)(Aptr + kadv),
                    (__attribute__((address_space(3))) void*)(An + tid * 8), 16, 0, 0);
#pragma unroll
            for (int j = 0; j < 8; ++j)
                __builtin_amdgcn_global_load_lds(
                    (const __attribute__((address_space(1))) void*)(Bptr + (size_t)j * 32 * 3072 + kadv),
                    (__attribute__((address_space(3))) void*)(Bn + (j * 256 + tid) * 8), 16, 0, 0);
        }
#pragma unroll
        for (int h = 0; h < 2; ++h) {
            bf16x8 a = *(const bf16x8*)&Ac[aoff[h]];
#pragma unroll
            for (int ni = 0; ni < 4; ++ni) {
                bf16x8 b = *(const bf16x8*)&Bc[boff[ni][h]];
                acc[ni] = __builtin_amdgcn_mfma_f32_16x16x32_bf16(a, b, acc[ni], 0, 0, 0);
            }
        }
    }

    __syncthreads();                          // phase-1 reads done; reuse LDS

    // x1 = gelu(acc + b1) -> bf16 LDS (16 x 264)
#pragma unroll
    for (int ni = 0; ni < 4; ++ni) {
        const int col = wid * 64 + ni * 16 + l16;
        const float bn = b1[col];
#pragma unroll
        for (int rr = 0; rr < 4; ++rr) {
            const int row = quad * 4 + rr;
            x1s[row * 264 + col] = f2bf(gelu_exact(acc[ni][rr] + bn));
        }
    }
    // stage W2 fp32 -> bf16 LDS (128 x 264)
#pragma unroll
    for (int p = 0; p < 16; ++p) {
        const int v = p * 256 + tid;
        const int r = v >> 5;                 // 0..127
        const int c = (v & 31) * 8;           // 0..248
        const float* src = W2f + (size_t)r * 256 + c;
        float4 f0 = *(const float4*)src;
        float4 f1 = *(const float4*)(src + 4);
        ushort4 u0, u1;
        u0.x = f2bf(f0.x); u0.y = f2bf(f0.y); u0.z = f2bf(f0.z); u0.w = f2bf(f0.w);
        u1.x = f2bf(f1.x); u1.y = f2bf(f1.y); u1.z = f2bf(f1.z); u1.w = f2bf(f1.w);
        *(ushort4*)&w2s[r * 264 + c] = u0;
        *(ushort4*)&w2s[r * 264 + c + 4] = u1;
    }
    __syncthreads();

    // GEMM2: x2acc[16][128] = x1 @ W2^T, wave owns 32 N-cols
    f32x4 acc2[2] = {};
#pragma unroll
    for (int h2 = 0; h2 < 8; ++h2) {
        const int k = h2 * 32 + quad * 8;
        bf16x8 a = *(const bf16x8*)&x1s[l16 * 264 + k];
#pragma unroll
        for (int ni = 0; ni < 2; ++ni) {
            const int r = wid * 32 + ni * 16 + l16;
            bf16x8 b = *(const bf16x8*)&w2s[r * 264 + k];
            acc2[ni] = __builtin_amdgcn_mfma_f32_16x16x32_bf16(a, b, acc2[ni], 0, 0, 0);
        }
    }

    // x2 = gelu(acc2 + b2) -> fp32 LDS (16 x 132)
#pragma unroll
    for (int ni = 0; ni < 2; ++ni) {
        const int col = wid * 32 + ni * 16 + l16;
        const float bn = b2[col];
#pragma unroll
        for (int rr = 0; rr < 4; ++rr) {
            const int row = quad * 4 + rr;
            x2s[row * 132 + col] = gelu_exact(acc2[ni][rr] + bn);
        }
    }
    __syncthreads();

    // head: 16 threads per pair, 8 cols each
    const int p = tid >> 4;                   // 0..15
    const int cg = tid & 15;
    const int c0 = cg * 8;
    float a0 = 0.f, a1 = 0.f;
#pragma unroll
    for (int j = 0; j < 8; ++j) {
        const float xv = x2s[p * 132 + c0 + j];
        a0 += xv * W3[c0 + j];
        a1 += xv * W3[128 + c0 + j];
    }
    a0 += __shfl_xor(a0, 1); a0 += __shfl_xor(a0, 2);
    a0 += __shfl_xor(a0, 4); a0 += __shfl_xor(a0, 8);
    a1 += __shfl_xor(a1, 1); a1 += __shfl_xor(a1, 2);
    a1 += __shfl_xor(a1, 4); a1 += __shfl_xor(a1, 8);
    if (cg == 0) {
        const int pair = m0 + p;
        const float mk = (mask[pair] >= 0.5f) ? 1.0f : 0.0f;
        out[pair * 2 + 0] = ((1.0f / (1.0f + expf(-(a0 + b3[0])))) * 8.0f + 1.0f) * mk;
        out[pair * 2 + 1] = ((1.0f / (1.0f + expf(-(a1 + b3[1])))) * 8.0f + 1.0f) * mk;
    }
}

// ---------------------------------------------------------------------------
extern "C" void kernel_launch(void* const* d_in, const int* in_sizes, int n_in,
                              void* d_out, int out_size, void* d_ws, size_t ws_size,
                              hipStream_t stream) {
    const float* hs   = (const float*)d_in[0];
    const int*   spans= (const int*)d_in[1];
    const float* mask = (const float*)d_in[2];
    const float* W1   = (const float*)d_in[3];
    const float* b1   = (const float*)d_in[4];
    const float* W2   = (const float*)d_in[5];
    const float* b2   = (const float*)d_in[6];
    const float* W3   = (const float*)d_in[7];
    const float* b3   = (const float*)d_in[8];
    float* out = (float*)d_out;

    // ws: hp bf16 4096x3072 [0, 25165824); w1b bf16 256x3072 [25165824, +1.5MB)
    unsigned short* hp  = (unsigned short*)d_ws;
    unsigned short* w1b = (unsigned short*)((char*)d_ws + 25165824);

    prep_kernel<<<dim3(4864), dim3(256), 0, stream>>>(hs, spans, W1, hp, w1b);
    mlp_all<<<dim3(256), dim3(256), 0, stream>>>(hp, w1b, b1, W2, b2, W3, b3, mask, out);
}

// Round 9
// 157.163 us; speedup vs baseline: 1.3059x; 1.0093x over previous
//
#include <hip/hip_runtime.h>
#include <hip/hip_bf16.h>
#include <math.h>

typedef __bf16 bf16x8 __attribute__((ext_vector_type(8)));
typedef float f32x4 __attribute__((ext_vector_type(4)));

__device__ __forceinline__ unsigned short f2bf(float x) {
    union { float f; unsigned int u; } v; v.f = x;
    unsigned int r = v.u + 0x7fffu + ((v.u >> 16) & 1u);  // round-to-nearest-even
    return (unsigned short)(r >> 16);
}
__device__ __forceinline__ float gelu_exact(float v) {
    return 0.5f * v * (1.0f + erff(v * 0.70710678118654752f));
}

// ---------------------------------------------------------------------------
// prep: blocks [0,4096)   -> span pooling into hp (4096 x 3072 bf16)
//       blocks [4096,4864)-> W1 fp32 -> bf16 (256x3072)
// ---------------------------------------------------------------------------
__global__ __launch_bounds__(256) void prep_kernel(const float* __restrict__ hs,
                                                   const int* __restrict__ spans,
                                                   const float* __restrict__ W1,
                                                   unsigned short* __restrict__ hp,
                                                   unsigned short* __restrict__ w1b) {
    const int blk = blockIdx.x;
    const int tid = threadIdx.x;

    if (blk >= 4096) {                        // W1 convert: 196608 float4s
        const int i = (blk - 4096) * 256 + tid;
        float4 f = ((const float4*)W1)[i];
        ushort4 u;
        u.x = f2bf(f.x); u.y = f2bf(f.y); u.z = f2bf(f.z); u.w = f2bf(f.w);
        ((ushort4*)w1b)[i] = u;
        return;
    }

    const int pair = blk;                     // b*Q + q, Q=128
    const int b = pair >> 7;

    // dtype probe: int64 spans -> word 1 is high half of asp_s[0] (== 0);
    // int32 spans -> it's asp_e[0] which is always >= 2.
    const bool is64 = (spans[1] == 0);
    int s_a, e_a, s_o, e_o;
    if (is64) {
        s_a = spans[(pair * 4 + 0) * 2]; e_a = spans[(pair * 4 + 1) * 2];
        s_o = spans[(pair * 4 + 2) * 2]; e_o = spans[(pair * 4 + 3) * 2];
    } else {
        s_a = spans[pair * 4 + 0]; e_a = spans[pair * 4 + 1];
        s_o = spans[pair * 4 + 2]; e_o = spans[pair * 4 + 3];
    }

    const float4* base = (const float4*)hs + (size_t)b * 512 * 256;  // L=512, H/4=256

    float4 A, O;
    if (s_a >= 2 && e_a >= s_a) {
        float sx = 0.f, sy = 0.f, sz = 0.f, sw = 0.f;
        for (int t = s_a; t <= e_a; ++t) {
            float4 v = base[t * 256 + tid];
            sx += v.x; sy += v.y; sz += v.z; sw += v.w;
        }
        float inv = 1.0f / (float)(e_a - s_a + 1);
        A.x = sx * inv; A.y = sy * inv; A.z = sz * inv; A.w = sw * inv;
    } else {
        A = base[256 + tid];                  // sep token, row 1
    }
    if (s_o >= 2 && e_o >= s_o) {
        float sx = 0.f, sy = 0.f, sz = 0.f, sw = 0.f;
        for (int t = s_o; t <= e_o; ++t) {
            float4 v = base[t * 256 + tid];
            sx += v.x; sy += v.y; sz += v.z; sw += v.w;
        }
        float inv = 1.0f / (float)(e_o - s_o + 1);
        O.x = sx * inv; O.y = sy * inv; O.z = sz * inv; O.w = sw * inv;
    } else {
        O = base[256 + tid];
    }

    unsigned short* row = hp + (size_t)pair * 3072;
    const int d = tid * 4;
    ushort4 pa, po, pp;
    pa.x = f2bf(A.x); pa.y = f2bf(A.y); pa.z = f2bf(A.z); pa.w = f2bf(A.w);
    po.x = f2bf(O.x); po.y = f2bf(O.y); po.z = f2bf(O.z); po.w = f2bf(O.w);
    pp.x = f2bf(A.x * O.x); pp.y = f2bf(A.y * O.y);
    pp.z = f2bf(A.z * O.z); pp.w = f2bf(A.w * O.w);
    *(ushort4*)(row + d) = pa;
    *(ushort4*)(row + 1024 + d) = po;
    *(ushort4*)(row + 2048 + d) = pp;
}

// ---------------------------------------------------------------------------
// gemm1_gelu: x1 = gelu(hp @ w1b^T + b1) -> bf16, NO split-K, NO atomics.
// BM=16, BN=64, BK=64, K=3072 (48 iters). grid (256, 4) = 1024 blocks.
// 4 waves; wave w owns N rows [n0+w*16, +16): 1 MFMA 16x16x32 per h (2/iter).
// LDS 20 KB -> ~4 blocks/CU resident; barrier drains overlap ACROSS blocks.
// Double-buffered global_load_lds (width 16) with XOR chunk swizzle.
// ---------------------------------------------------------------------------
__global__ __launch_bounds__(256, 8) void gemm1_gelu(const unsigned short* __restrict__ A,
                                                     const unsigned short* __restrict__ Bw,
                                                     const float* __restrict__ b1,
                                                     unsigned short* __restrict__ x1) {
    __shared__ __align__(16) unsigned short As[2][16 * 64];
    __shared__ __align__(16) unsigned short Bs[2][64 * 64];

    const int tid = threadIdx.x;
    const int lane = tid & 63;
    const int wid = tid >> 6;
    const int quad = lane >> 4;
    const int l16 = lane & 15;
    const int m0 = blockIdx.x * 16;
    const int n0 = blockIdx.y * 64;

    // staging source (XOR chunk swizzle): slot s -> row s>>3, pchunk s&7
    // holds global chunk (s&7)^(row&7)
    const int srow = tid >> 3;                // 0..31
    const int lch = (tid & 7) ^ (srow & 7);
    const unsigned short* Aptr = A + (size_t)(m0 + srow) * 3072 + lch * 8;   // tid<128
    const unsigned short* Bptr = Bw + (size_t)(n0 + srow) * 3072 + lch * 8;  // +j*32 rows

    // fragment LDS offsets (halfwords)
    int aoff[2], boff[2];
#pragma unroll
    for (int h = 0; h < 2; ++h) {
        int pc = (h * 4 + quad) ^ (l16 & 7);
        aoff[h] = l16 * 64 + pc * 8;
        const int brow = wid * 16 + l16;
        pc = (h * 4 + quad) ^ (brow & 7);
        boff[h] = brow * 64 + pc * 8;
    }

    f32x4 acc = {};

    // prologue: tile 0 -> buffer 0
    if (tid < 128)
        __builtin_amdgcn_global_load_lds(
            (const __attribute__((address_space(1))) void*)Aptr,
            (__attribute__((address_space(3))) void*)(&As[0][tid * 8]), 16, 0, 0);
#pragma unroll
    for (int j = 0; j < 2; ++j)
        __builtin_amdgcn_global_load_lds(
            (const __attribute__((address_space(1))) void*)(Bptr + (size_t)j * 32 * 3072),
            (__attribute__((address_space(3))) void*)(&Bs[0][(j * 256 + tid) * 8]), 16, 0, 0);

    for (int it = 0; it < 48; ++it) {
        const int cur = it & 1;
        __syncthreads();                      // drains pending stage (vmcnt 0)
        if (it + 1 < 48) {
            const int nxt = cur ^ 1;
            const int kadv = (it + 1) * 64;
            if (tid < 128)
                __builtin_amdgcn_global_load_lds(
                    (const __attribute__((address_space(1))) void*)(Aptr + kadv),
                    (__attribute__((address_space(3))) void*)(&As[nxt][tid * 8]), 16, 0, 0);
#pragma unroll
            for (int j = 0; j < 2; ++j)
                __builtin_amdgcn_global_load_lds(
                    (const __attribute__((address_space(1))) void*)(Bptr + (size_t)j * 32 * 3072 + kadv),
                    (__attribute__((address_space(3))) void*)(&Bs[nxt][(j * 256 + tid) * 8]), 16, 0, 0);
        }
#pragma unroll
        for (int h = 0; h < 2; ++h) {
            bf16x8 a = *(const bf16x8*)&As[cur][aoff[h]];
            bf16x8 b = *(const bf16x8*)&Bs[cur][boff[h]];
            acc = __builtin_amdgcn_mfma_f32_16x16x32_bf16(a, b, acc, 0, 0, 0);
        }
    }

    // epilogue: bias + gelu -> bf16; C/D map: col=l16, row=quad*4+reg
    const int n = n0 + wid * 16 + l16;
    const float bn = b1[n];
#pragma unroll
    for (int rr = 0; rr < 4; ++rr) {
        const int m = m0 + quad * 4 + rr;
        x1[(size_t)m * 256 + n] = f2bf(gelu_exact(acc[rr] + bn));
    }
}

// ---------------------------------------------------------------------------
// Fused GEMM2 + bias + GELU + head: 32 pairs/block, grid 128.
// ---------------------------------------------------------------------------
__global__ __launch_bounds__(256) void mlp2_head(const unsigned short* __restrict__ x1,
                                                 const float* __restrict__ W2f,
                                                 const float* __restrict__ b2,
                                                 const float* __restrict__ W3,
                                                 const float* __restrict__ b3,
                                                 const float* __restrict__ mask,
                                                 float* __restrict__ out) {
    __shared__ __align__(16) unsigned short Xs[32][72];
    __shared__ __align__(16) unsigned short Ws[128][72];
    __shared__ float X2[32][132];

    const int tid = threadIdx.x;
    const int lane = tid & 63;
    const int wid = tid >> 6;
    const int wM = (wid >> 1) * 16;   // waves 2x2: wave tile 16 x 64
    const int wN = (wid & 1) * 64;
    const int quad = lane >> 4;
    const int l16 = lane & 15;
    const int m0 = blockIdx.x * 32;

    f32x4 acc[4] = {};

    for (int k0 = 0; k0 < 256; k0 += 64) {
        {   // stage Xs 32x64 bf16
            const int r = tid >> 3, c = (tid & 7) * 8;
            *(uint4*)&Xs[r][c] = *(const uint4*)(x1 + (size_t)(m0 + r) * 256 + k0 + c);
        }
#pragma unroll
        for (int p = 0; p < 4; ++p) {   // stage Ws 128x64 from fp32
            const int v = tid + p * 256;
            const int r = v >> 3, c = (v & 7) * 8;
            const float* src = W2f + (size_t)r * 256 + k0 + c;
            float4 f0 = *(const float4*)src;
            float4 f1 = *(const float4*)(src + 4);
            ushort4 u;
            u.x = f2bf(f0.x); u.y = f2bf(f0.y); u.z = f2bf(f0.z); u.w = f2bf(f0.w);
            *(ushort4*)&Ws[r][c] = u;
            u.x = f2bf(f1.x); u.y = f2bf(f1.y); u.z = f2bf(f1.z); u.w = f2bf(f1.w);
            *(ushort4*)&Ws[r][c + 4] = u;
        }
        __syncthreads();
#pragma unroll
        for (int kk = 0; kk < 64; kk += 32) {
            bf16x8 a = *(const bf16x8*)&Xs[wM + l16][kk + quad * 8];
#pragma unroll
            for (int ni = 0; ni < 4; ++ni) {
                bf16x8 b = *(const bf16x8*)&Ws[wN + ni * 16 + l16][kk + quad * 8];
                acc[ni] = __builtin_amdgcn_mfma_f32_16x16x32_bf16(a, b, acc[ni], 0, 0, 0);
            }
        }
        __syncthreads();
    }

#pragma unroll
    for (int ni = 0; ni < 4; ++ni) {
        const int n = wN + ni * 16 + l16;
        const float bn = b2[n];
#pragma unroll
        for (int rr = 0; rr < 4; ++rr) {
            const int m = wM + quad * 4 + rr;
            X2[m][n] = gelu_exact(acc[ni][rr] + bn);
        }
    }
    __syncthreads();

    const int p = tid >> 3;           // pair-in-block 0..31
    const int cc = (tid & 7) * 16;
    float a0 = 0.f, a1 = 0.f;
#pragma unroll
    for (int j = 0; j < 16; ++j) {
        const float xv = X2[p][cc + j];
        a0 += xv * W3[cc + j];
        a1 += xv * W3[128 + cc + j];
    }
    a0 += __shfl_xor(a0, 1); a0 += __shfl_xor(a0, 2); a0 += __shfl_xor(a0, 4);
    a1 += __shfl_xor(a1, 1); a1 += __shfl_xor(a1, 2); a1 += __shfl_xor(a1, 4);
    if ((tid & 7) == 0) {
        const int pair = m0 + p;
        const float mk = (mask[pair] >= 0.5f) ? 1.0f : 0.0f;
        out[pair * 2 + 0] = ((1.0f / (1.0f + expf(-(a0 + b3[0])))) * 8.0f + 1.0f) * mk;
        out[pair * 2 + 1] = ((1.0f / (1.0f + expf(-(a1 + b3[1])))) * 8.0f + 1.0f) * mk;
    }
}

// ---------------------------------------------------------------------------
extern "C" void kernel_launch(void* const* d_in, const int* in_sizes, int n_in,
                              void* d_out, int out_size, void* d_ws, size_t ws_size,
                              hipStream_t stream) {
    const float* hs   = (const float*)d_in[0];
    const int*   spans= (const int*)d_in[1];
    const float* mask = (const float*)d_in[2];
    const float* W1   = (const float*)d_in[3];
    const float* b1   = (const float*)d_in[4];
    const float* W2   = (const float*)d_in[5];
    const float* b2   = (const float*)d_in[6];
    const float* W3   = (const float*)d_in[7];
    const float* b3   = (const float*)d_in[8];
    float* out = (float*)d_out;

    // ws: hp bf16 4096x3072 [0, 25165824); w1b bf16 256x3072 [25165824, +1.5MB);
    // x1 bf16 4096x256 [26738688, +2MB).
    unsigned short* hp  = (unsigned short*)d_ws;
    unsigned short* w1b = (unsigned short*)((char*)d_ws + 25165824);
    unsigned short* x1  = (unsigned short*)((char*)d_ws + 26738688);

    prep_kernel<<<dim3(4864), dim3(256), 0, stream>>>(hs, spans, W1, hp, w1b);
    gemm1_gelu<<<dim3(256, 4), dim3(256), 0, stream>>>(hp, w1b, b1, x1);
    mlp2_head<<<dim3(128), dim3(256), 0, stream>>>(x1, W2, b2, W3, b3, mask, out);
}

// Round 10
// 148.672 us; speedup vs baseline: 1.3805x; 1.0571x over previous
//
#include <hip/hip_runtime.h>
#include <hip/hip_bf16.h>
#include <math.h>

typedef __bf16 bf16x8 __attribute__((ext_vector_type(8)));
typedef float f32x4 __attribute__((ext_vector_type(4)));

__device__ __forceinline__ unsigned short f2bf(float x) {
    union { float f; unsigned int u; } v; v.f = x;
    unsigned int r = v.u + 0x7fffu + ((v.u >> 16) & 1u);  // round-to-nearest-even
    return (unsigned short)(r >> 16);
}
__device__ __forceinline__ float gelu_exact(float v) {
    return 0.5f * v * (1.0f + erff(v * 0.70710678118654752f));
}

// ---------------------------------------------------------------------------
// prep: blocks [0,4096)    -> span pooling into hp (4096 x 3072 bf16)
//       blocks [4096,4864) -> W1 fp32 -> bf16 (256x3072)
//       blocks [4864,4896) -> W2 fp32 -> bf16 (128x256)
// ---------------------------------------------------------------------------
__global__ __launch_bounds__(256) void prep_kernel(const float* __restrict__ hs,
                                                   const int* __restrict__ spans,
                                                   const float* __restrict__ W1,
                                                   const float* __restrict__ W2,
                                                   unsigned short* __restrict__ hp,
                                                   unsigned short* __restrict__ w1b,
                                                   unsigned short* __restrict__ w2b) {
    const int blk = blockIdx.x;
    const int tid = threadIdx.x;

    if (blk >= 4096) {
        if (blk < 4864) {                     // W1 convert: 196608 float4s
            const int i = (blk - 4096) * 256 + tid;
            float4 f = ((const float4*)W1)[i];
            ushort4 u;
            u.x = f2bf(f.x); u.y = f2bf(f.y); u.z = f2bf(f.z); u.w = f2bf(f.w);
            ((ushort4*)w1b)[i] = u;
        } else {                              // W2 convert: 8192 float4s
            const int i = (blk - 4864) * 256 + tid;
            float4 f = ((const float4*)W2)[i];
            ushort4 u;
            u.x = f2bf(f.x); u.y = f2bf(f.y); u.z = f2bf(f.z); u.w = f2bf(f.w);
            ((ushort4*)w2b)[i] = u;
        }
        return;
    }

    const int pair = blk;                     // b*Q + q, Q=128
    const int b = pair >> 7;

    // dtype probe: int64 spans -> word 1 is high half of asp_s[0] (== 0);
    // int32 spans -> it's asp_e[0] which is always >= 2.
    const bool is64 = (spans[1] == 0);
    int s_a, e_a, s_o, e_o;
    if (is64) {
        s_a = spans[(pair * 4 + 0) * 2]; e_a = spans[(pair * 4 + 1) * 2];
        s_o = spans[(pair * 4 + 2) * 2]; e_o = spans[(pair * 4 + 3) * 2];
    } else {
        s_a = spans[pair * 4 + 0]; e_a = spans[pair * 4 + 1];
        s_o = spans[pair * 4 + 2]; e_o = spans[pair * 4 + 3];
    }

    const float4* base = (const float4*)hs + (size_t)b * 512 * 256;  // L=512, H/4=256

    float4 A, O;
    if (s_a >= 2 && e_a >= s_a) {
        float sx = 0.f, sy = 0.f, sz = 0.f, sw = 0.f;
        for (int t = s_a; t <= e_a; ++t) {
            float4 v = base[t * 256 + tid];
            sx += v.x; sy += v.y; sz += v.z; sw += v.w;
        }
        float inv = 1.0f / (float)(e_a - s_a + 1);
        A.x = sx * inv; A.y = sy * inv; A.z = sz * inv; A.w = sw * inv;
    } else {
        A = base[256 + tid];                  // sep token, row 1
    }
    if (s_o >= 2 && e_o >= s_o) {
        float sx = 0.f, sy = 0.f, sz = 0.f, sw = 0.f;
        for (int t = s_o; t <= e_o; ++t) {
            float4 v = base[t * 256 + tid];
            sx += v.x; sy += v.y; sz += v.z; sw += v.w;
        }
        float inv = 1.0f / (float)(e_o - s_o + 1);
        O.x = sx * inv; O.y = sy * inv; O.z = sz * inv; O.w = sw * inv;
    } else {
        O = base[256 + tid];
    }

    unsigned short* row = hp + (size_t)pair * 3072;
    const int d = tid * 4;
    ushort4 pa, po, pp;
    pa.x = f2bf(A.x); pa.y = f2bf(A.y); pa.z = f2bf(A.z); pa.w = f2bf(A.w);
    po.x = f2bf(O.x); po.y = f2bf(O.y); po.z = f2bf(O.z); po.w = f2bf(O.w);
    pp.x = f2bf(A.x * O.x); pp.y = f2bf(A.y * O.y);
    pp.z = f2bf(A.z * O.z); pp.w = f2bf(A.w * O.w);
    *(ushort4*)(row + d) = pa;
    *(ushort4*)(row + 1024 + d) = po;
    *(ushort4*)(row + 2048 + d) = pp;
}

// ---------------------------------------------------------------------------
// gemm1_gelu v2: x1 = gelu(hp @ w1b^T + b1) -> bf16. No split-K, no atomics.
// BM=32, BN=64, BK=128, K=3072 (24 iters). grid (128, 4) = 512 blocks (2/CU).
// LDS 48 KB double-buffered; 4 waves, wave owns 16 N-cols x 32 M-rows
// (2 MFMA 16x16x32 per K-fragment h, 4 h per iter = 8 MFMA/iter/wave).
// global_load_lds width=16 staging with XOR chunk swizzle (16 chunks/row,
// pc = ((c&7)^(row&7)) | (c&8)); read side agrees -> 2-way banks (free).
// ---------------------------------------------------------------------------
__global__ __launch_bounds__(256, 2) void gemm1_gelu(const unsigned short* __restrict__ A,
                                                     const unsigned short* __restrict__ Bw,
                                                     const float* __restrict__ b1,
                                                     unsigned short* __restrict__ x1) {
    __shared__ __align__(16) unsigned short As[2][32 * 128];
    __shared__ __align__(16) unsigned short Bs[2][64 * 128];

    const int tid = threadIdx.x;
    const int lane = tid & 63;
    const int wid = tid >> 6;
    const int quad = lane >> 4;
    const int l16 = lane & 15;
    const int m0 = blockIdx.x * 32;
    const int n0 = blockIdx.y * 64;

    // staging: slot s -> row = s>>4, chunk c = s&15; source chunk XOR-swizzled
    const int arow = tid >> 4;                // A: p*256+tid -> row = arow + p*16
    const int ac = tid & 15;
    const unsigned short* Aptr[2];
#pragma unroll
    for (int p = 0; p < 2; ++p) {
        const int row = arow + p * 16;
        const int lch = ((ac & 7) ^ (row & 7)) | (ac & 8);
        Aptr[p] = A + (size_t)(m0 + row) * 3072 + lch * 8;
    }
    const unsigned short* Bptr[4];
#pragma unroll
    for (int p = 0; p < 4; ++p) {
        const int row = arow + p * 16;        // B rows 0..63
        const int lch = ((ac & 7) ^ (row & 7)) | (ac & 8);
        Bptr[p] = Bw + (size_t)(n0 + row) * 3072 + lch * 8;
    }

    // fragment LDS offsets (halfwords): K-frag h, chunk c = h*4+quad
    int aoff[2][4], boff[4];
#pragma unroll
    for (int h = 0; h < 4; ++h) {
        const int c = h * 4 + quad;
#pragma unroll
        for (int mh = 0; mh < 2; ++mh) {
            const int row = mh * 16 + l16;
            const int pc = ((c & 7) ^ (row & 7)) | (c & 8);
            aoff[mh][h] = row * 128 + pc * 8;
        }
        const int brow = wid * 16 + l16;
        const int pcb = ((c & 7) ^ (brow & 7)) | (c & 8);
        boff[h] = brow * 128 + pcb * 8;
    }

    f32x4 acc[2] = {};

    // prologue: tile 0 -> buffer 0
#pragma unroll
    for (int p = 0; p < 2; ++p)
        __builtin_amdgcn_global_load_lds(
            (const __attribute__((address_space(1))) void*)Aptr[p],
            (__attribute__((address_space(3))) void*)(&As[0][(p * 256 + tid) * 8]), 16, 0, 0);
#pragma unroll
    for (int p = 0; p < 4; ++p)
        __builtin_amdgcn_global_load_lds(
            (const __attribute__((address_space(1))) void*)Bptr[p],
            (__attribute__((address_space(3))) void*)(&Bs[0][(p * 256 + tid) * 8]), 16, 0, 0);

    for (int it = 0; it < 24; ++it) {
        const int cur = it & 1;
        __syncthreads();                      // drains pending stage (vmcnt 0)
        if (it + 1 < 24) {
            const int nxt = cur ^ 1;
            const int kadv = (it + 1) * 128;  // halfwords along K
#pragma unroll
            for (int p = 0; p < 2; ++p)
                __builtin_amdgcn_global_load_lds(
                    (const __attribute__((address_space(1))) void*)(Aptr[p] + kadv),
                    (__attribute__((address_space(3))) void*)(&As[nxt][(p * 256 + tid) * 8]), 16, 0, 0);
#pragma unroll
            for (int p = 0; p < 4; ++p)
                __builtin_amdgcn_global_load_lds(
                    (const __attribute__((address_space(1))) void*)(Bptr[p] + kadv),
                    (__attribute__((address_space(3))) void*)(&Bs[nxt][(p * 256 + tid) * 8]), 16, 0, 0);
        }
#pragma unroll
        for (int h = 0; h < 4; ++h) {
            bf16x8 b = *(const bf16x8*)&Bs[cur][boff[h]];
#pragma unroll
            for (int mh = 0; mh < 2; ++mh) {
                bf16x8 a = *(const bf16x8*)&As[cur][aoff[mh][h]];
                acc[mh] = __builtin_amdgcn_mfma_f32_16x16x32_bf16(a, b, acc[mh], 0, 0, 0);
            }
        }
    }

    // epilogue: bias + gelu -> bf16; C/D map: col=l16, row=quad*4+reg
    const int n = n0 + wid * 16 + l16;
    const float bn = b1[n];
#pragma unroll
    for (int mh = 0; mh < 2; ++mh) {
#pragma unroll
        for (int rr = 0; rr < 4; ++rr) {
            const int m = m0 + mh * 16 + quad * 4 + rr;
            x1[(size_t)m * 256 + n] = f2bf(gelu_exact(acc[mh][rr] + bn));
        }
    }
}

// ---------------------------------------------------------------------------
// Fused GEMM2 + bias + GELU + head: 32 pairs/block, grid 128. W2 pre-bf16.
// ---------------------------------------------------------------------------
__global__ __launch_bounds__(256) void mlp2_head(const unsigned short* __restrict__ x1,
                                                 const unsigned short* __restrict__ w2b,
                                                 const float* __restrict__ b2,
                                                 const float* __restrict__ W3,
                                                 const float* __restrict__ b3,
                                                 const float* __restrict__ mask,
                                                 float* __restrict__ out) {
    __shared__ __align__(16) unsigned short Xs[32][72];
    __shared__ __align__(16) unsigned short Ws[128][72];
    __shared__ float X2[32][132];

    const int tid = threadIdx.x;
    const int lane = tid & 63;
    const int wid = tid >> 6;
    const int wM = (wid >> 1) * 16;   // waves 2x2: wave tile 16 x 64
    const int wN = (wid & 1) * 64;
    const int quad = lane >> 4;
    const int l16 = lane & 15;
    const int m0 = blockIdx.x * 32;

    f32x4 acc[4] = {};

    for (int k0 = 0; k0 < 256; k0 += 64) {
        {   // stage Xs 32x64 bf16
            const int r = tid >> 3, c = (tid & 7) * 8;
            *(uint4*)&Xs[r][c] = *(const uint4*)(x1 + (size_t)(m0 + r) * 256 + k0 + c);
        }
#pragma unroll
        for (int p = 0; p < 4; ++p) {   // stage Ws 128x64 bf16
            const int v = tid + p * 256;
            const int r = v >> 3, c = (v & 7) * 8;
            *(uint4*)&Ws[r][c] = *(const uint4*)(w2b + (size_t)r * 256 + k0 + c);
        }
        __syncthreads();
#pragma unroll
        for (int kk = 0; kk < 64; kk += 32) {
            bf16x8 a = *(const bf16x8*)&Xs[wM + l16][kk + quad * 8];
#pragma unroll
            for (int ni = 0; ni < 4; ++ni) {
                bf16x8 b = *(const bf16x8*)&Ws[wN + ni * 16 + l16][kk + quad * 8];
                acc[ni] = __builtin_amdgcn_mfma_f32_16x16x32_bf16(a, b, acc[ni], 0, 0, 0);
            }
        }
        __syncthreads();
    }

#pragma unroll
    for (int ni = 0; ni < 4; ++ni) {
        const int n = wN + ni * 16 + l16;
        const float bn = b2[n];
#pragma unroll
        for (int rr = 0; rr < 4; ++rr) {
            const int m = wM + quad * 4 + rr;
            X2[m][n] = gelu_exact(acc[ni][rr] + bn);
        }
    }
    __syncthreads();

    const int p = tid >> 3;           // pair-in-block 0..31
    const int cc = (tid & 7) * 16;
    float a0 = 0.f, a1 = 0.f;
#pragma unroll
    for (int j = 0; j < 16; ++j) {
        const float xv = X2[p][cc + j];
        a0 += xv * W3[cc + j];
        a1 += xv * W3[128 + cc + j];
    }
    a0 += __shfl_xor(a0, 1); a0 += __shfl_xor(a0, 2); a0 += __shfl_xor(a0, 4);
    a1 += __shfl_xor(a1, 1); a1 += __shfl_xor(a1, 2); a1 += __shfl_xor(a1, 4);
    if ((tid & 7) == 0) {
        const int pair = m0 + p;
        const float mk = (mask[pair] >= 0.5f) ? 1.0f : 0.0f;
        out[pair * 2 + 0] = ((1.0f / (1.0f + expf(-(a0 + b3[0])))) * 8.0f + 1.0f) * mk;
        out[pair * 2 + 1] = ((1.0f / (1.0f + expf(-(a1 + b3[1])))) * 8.0f + 1.0f) * mk;
    }
}

// ---------------------------------------------------------------------------
extern "C" void kernel_launch(void* const* d_in, const int* in_sizes, int n_in,
                              void* d_out, int out_size, void* d_ws, size_t ws_size,
                              hipStream_t stream) {
    const float* hs   = (const float*)d_in[0];
    const int*   spans= (const int*)d_in[1];
    const float* mask = (const float*)d_in[2];
    const float* W1   = (const float*)d_in[3];
    const float* b1   = (const float*)d_in[4];
    const float* W2   = (const float*)d_in[5];
    const float* b2   = (const float*)d_in[6];
    const float* W3   = (const float*)d_in[7];
    const float* b3   = (const float*)d_in[8];
    float* out = (float*)d_out;

    // ws: hp bf16 4096x3072 [0, 25165824); w1b bf16 256x3072 [25165824, +1.5MB);
    // x1 bf16 4096x256 [26738688, +2MB); w2b bf16 128x256 [28835840, +64KB).
    unsigned short* hp  = (unsigned short*)d_ws;
    unsigned short* w1b = (unsigned short*)((char*)d_ws + 25165824);
    unsigned short* x1  = (unsigned short*)((char*)d_ws + 26738688);
    unsigned short* w2b = (unsigned short*)((char*)d_ws + 28835840);

    prep_kernel<<<dim3(4896), dim3(256), 0, stream>>>(hs, spans, W1, W2, hp, w1b, w2b);
    gemm1_gelu<<<dim3(128, 4), dim3(256), 0, stream>>>(hp, w1b, b1, x1);
    mlp2_head<<<dim3(128), dim3(256), 0, stream>>>(x1, w2b, b2, W3, b3, mask, out);
}